// Round 1
// baseline (290.389 us; speedup 1.0000x reference)
//
#include <hip/hip_runtime.h>
#include <math.h>

// Mamba-like block with L=1: scan degenerates (h=dBx), A_log unused,
// depthwise conv reduces to last-tap: xc = silu(xs*conv_w[3] + conv_b).
// Per layer: LN -> GEMM1(256->1024) -> silu/conv -> GEMM2(512->144)
//   -> bc=Bm.Cm, dt=softplus(dtr@dtw+db) -> y=xc*(dt*bc+D)*silu(gate)
//   -> GEMM3(512->256) + out_b + residual.

#define NTOK 3200   // B*V = 8*400
#define DM   256
#define DI   512
#define NX   1024   // 2*DI
#define DTR  16
#define DS   64
#define NPJ  144    // DTR + 2*DS

__device__ __forceinline__ float sigf(float x){ return 1.0f/(1.0f+expf(-x)); }
__device__ __forceinline__ float siluf(float x){ return x*sigf(x); }
__device__ __forceinline__ float softplusf(float x){ return (x>20.f) ? x : log1pf(expf(x)); }

// ---------------- LayerNorm: one wave per token ----------------
__global__ __launch_bounds__(256) void ln_kernel(
    const float* __restrict__ x, const float* __restrict__ lw,
    const float* __restrict__ lb, float* __restrict__ xn)
{
    const int wave = threadIdx.x >> 6, lane = threadIdx.x & 63;
    const int tok  = blockIdx.x*4 + wave;
    const float4 v = *(const float4*)(x + tok*DM + lane*4);
    float s = v.x+v.y+v.z+v.w;
    #pragma unroll
    for (int o=32;o>=1;o>>=1) s += __shfl_xor(s,o,64);
    const float mu = s*(1.0f/DM);
    const float4 d = {v.x-mu, v.y-mu, v.z-mu, v.w-mu};
    float q = d.x*d.x+d.y*d.y+d.z*d.z+d.w*d.w;
    #pragma unroll
    for (int o=32;o>=1;o>>=1) q += __shfl_xor(q,o,64);
    const float r = rsqrtf(q*(1.0f/DM)+1e-5f);
    const float4 w = *(const float4*)(lw + lane*4);
    const float4 b = *(const float4*)(lb + lane*4);
    const float4 o4 = {d.x*r*w.x+b.x, d.y*r*w.y+b.y, d.z*r*w.z+b.z, d.w*r*w.w+b.w};
    *(float4*)(xn + tok*DM + lane*4) = o4;
}

// ---------------- GEMM1: xn(3200x256) @ in_w(256x1024) + epilogue ----------------
// tile 64x64, BK=16, 256 threads, 4x4 acc per thread
__global__ __launch_bounds__(256) void gemm1_kernel(
    const float* __restrict__ A, const float* __restrict__ W,
    const float* __restrict__ inb, const float* __restrict__ cw3,
    const float* __restrict__ cb, float* __restrict__ xc, float* __restrict__ sg)
{
    __shared__ float As[16][68];  // padded: 68 floats = 272B = 17*16B (keeps b128 align)
    __shared__ float Bs[16][64];
    const int tid = threadIdx.x;
    const int m0 = blockIdx.y*64, n0 = blockIdx.x*64;
    const int tm = tid>>4, tn = tid&15;
    const int la_m = tid>>2, la_k = (tid&3)*4;
    const int lb_k = tid>>4, lb_n = (tid&15)*4;
    float acc[4][4] = {};
    for (int k0=0;k0<DM;k0+=16){
        const float4 a4 = *(const float4*)(A + (m0+la_m)*DM + k0+la_k);
        As[la_k+0][la_m]=a4.x; As[la_k+1][la_m]=a4.y;
        As[la_k+2][la_m]=a4.z; As[la_k+3][la_m]=a4.w;
        *(float4*)(&Bs[lb_k][lb_n]) = *(const float4*)(W + (k0+lb_k)*NX + n0+lb_n);
        __syncthreads();
        #pragma unroll
        for (int kk=0;kk<16;kk++){
            const float4 a = *(const float4*)(&As[kk][tm*4]);
            const float4 b = *(const float4*)(&Bs[kk][tn*4]);
            const float av[4]={a.x,a.y,a.z,a.w};
            const float bv[4]={b.x,b.y,b.z,b.w};
            #pragma unroll
            for (int i=0;i<4;i++)
                #pragma unroll
                for (int j=0;j<4;j++) acc[i][j]=fmaf(av[i],bv[j],acc[i][j]);
        }
        __syncthreads();
    }
    const int nb = n0 + tn*4;
    #pragma unroll
    for (int i=0;i<4;i++){
        const int m = m0+tm*4+i;
        float4 o;
        float* po = &o.x;
        if (nb < DI){
            #pragma unroll
            for (int j=0;j<4;j++){
                float v = acc[i][j] + inb[nb+j];
                po[j] = siluf(v*cw3[nb+j]+cb[nb+j]);
            }
            *(float4*)(xc + m*DI + nb) = o;
        } else {
            #pragma unroll
            for (int j=0;j<4;j++){
                float v = acc[i][j] + inb[nb+j];
                po[j] = siluf(v);
            }
            *(float4*)(sg + m*DI + (nb-DI)) = o;
        }
    }
}

// ---------------- mid: GEMM2(512->144) + bc + dt + y (overwrites xc with y) ----------------
// 16 tokens per block, 256 threads
__global__ __launch_bounds__(256) void mid_kernel(
    float* __restrict__ xc, const float* __restrict__ sg,
    const float* __restrict__ xw, const float* __restrict__ dtw,
    const float* __restrict__ dtb, const float* __restrict__ Dp)
{
    __shared__ float xcs[16][512];   // 32 KB
    __shared__ float xws[32][144];   // 18 KB (k-chunk of xproj_w)
    __shared__ float dbl[16][144];   // 9 KB
    __shared__ float bcs[16];
    const int tid = threadIdx.x;
    const int tok0 = blockIdx.x*16;
    // stage xc tile
    #pragma unroll
    for (int i=0;i<8;i++){
        const int idx = (tid + i*256)*4;
        *(float4*)(&xcs[0][0] + idx) = *(const float4*)(xc + tok0*DI + idx);
    }
    __syncthreads();
    const int tt = tid>>4, tc = tid&15;
    float acc[9] = {};
    for (int k0=0;k0<DI;k0+=32){
        #pragma unroll
        for (int i=0;i<9;i++){
            const int idx = tid + i*256;  // float2 units, 32*144/2 = 2304
            *(float2*)(&xws[0][0] + idx*2) = *(const float2*)(xw + k0*NPJ + idx*2);
        }
        __syncthreads();
        #pragma unroll
        for (int kk=0;kk<32;kk++){
            const float a = xcs[tt][k0+kk];
            #pragma unroll
            for (int j=0;j<9;j++) acc[j] = fmaf(a, xws[kk][tc+j*16], acc[j]);
        }
        __syncthreads();
    }
    #pragma unroll
    for (int j=0;j<9;j++) dbl[tt][tc+j*16] = acc[j];
    __syncthreads();
    // bc[tok] = dot(Bm, Cm) over 64 states
    {
        float p = 0.f;
        #pragma unroll
        for (int j=0;j<4;j++){
            const int s = tc*4+j;
            p += dbl[tt][DTR+s]*dbl[tt][DTR+DS+s];
        }
        #pragma unroll
        for (int m=8;m>=1;m>>=1) p += __shfl_xor(p,m,16);
        if (tc==0) bcs[tt]=p;
    }
    __syncthreads();
    const float bc = bcs[tt];
    float dtr[DTR];
    #pragma unroll
    for (int r=0;r<DTR;r++) dtr[r]=dbl[tt][r];
    const int trow = tok0+tt;
    #pragma unroll
    for (int j=0;j<32;j++){
        const int d = tc + j*16;
        float dv = dtb[d];
        #pragma unroll
        for (int r=0;r<DTR;r++) dv = fmaf(dtr[r], dtw[r*DI+d], dv);
        dv = softplusf(dv);
        const float yv = xcs[tt][d]*(dv*bc + Dp[d]) * sg[trow*DI + d];
        xc[trow*DI + d] = yv;   // overwrite xc with y (this block owns these rows)
    }
}

// ---------------- GEMM3: y(3200x512) @ out_w(512x256) + out_b + residual ----------------
__global__ __launch_bounds__(256) void gemm3_kernel(
    const float* __restrict__ A, const float* __restrict__ W,
    const float* __restrict__ ob, const float* __restrict__ res,
    float* __restrict__ out)
{
    __shared__ float As[16][68];
    __shared__ float Bs[16][64];
    const int tid = threadIdx.x;
    const int m0 = blockIdx.y*64, n0 = blockIdx.x*64;
    const int tm = tid>>4, tn = tid&15;
    const int la_m = tid>>2, la_k = (tid&3)*4;
    const int lb_k = tid>>4, lb_n = (tid&15)*4;
    float acc[4][4] = {};
    for (int k0=0;k0<DI;k0+=16){
        const float4 a4 = *(const float4*)(A + (m0+la_m)*DI + k0+la_k);
        As[la_k+0][la_m]=a4.x; As[la_k+1][la_m]=a4.y;
        As[la_k+2][la_m]=a4.z; As[la_k+3][la_m]=a4.w;
        *(float4*)(&Bs[lb_k][lb_n]) = *(const float4*)(W + (k0+lb_k)*DM + n0+lb_n);
        __syncthreads();
        #pragma unroll
        for (int kk=0;kk<16;kk++){
            const float4 a = *(const float4*)(&As[kk][tm*4]);
            const float4 b = *(const float4*)(&Bs[kk][tn*4]);
            const float av[4]={a.x,a.y,a.z,a.w};
            const float bv[4]={b.x,b.y,b.z,b.w};
            #pragma unroll
            for (int i=0;i<4;i++)
                #pragma unroll
                for (int j=0;j<4;j++) acc[i][j]=fmaf(av[i],bv[j],acc[i][j]);
        }
        __syncthreads();
    }
    const int nb = n0 + tn*4;
    #pragma unroll
    for (int i=0;i<4;i++){
        const int m = m0+tm*4+i;
        const float4 rv = *(const float4*)(res + m*DM + nb);
        float4 o;
        o.x = acc[i][0] + ob[nb+0] + rv.x;
        o.y = acc[i][1] + ob[nb+1] + rv.y;
        o.z = acc[i][2] + ob[nb+2] + rv.z;
        o.w = acc[i][3] + ob[nb+3] + rv.w;
        *(float4*)(out + m*DM + nb) = o;
    }
}

extern "C" void kernel_launch(void* const* d_in, const int* in_sizes, int n_in,
                              void* d_out, int out_size, void* d_ws, size_t ws_size,
                              hipStream_t stream)
{
    const float* x    = (const float*)d_in[0];
    const float* ln_w = (const float*)d_in[1];
    const float* ln_b = (const float*)d_in[2];
    const float* in_w = (const float*)d_in[3];
    const float* in_b = (const float*)d_in[4];
    const float* cw   = (const float*)d_in[5];
    const float* cb   = (const float*)d_in[6];
    const float* xw   = (const float*)d_in[7];
    const float* dtw  = (const float*)d_in[8];
    const float* dtb  = (const float*)d_in[9];
    // d_in[10] = A_log: UNUSED. L==1 => scan state starts at 0, dA multiplies h0=0.
    const float* Dp   = (const float*)d_in[11];
    const float* ow   = (const float*)d_in[12];
    const float* ob   = (const float*)d_in[13];

    // workspace: xn (3200*256) + xc/y (3200*512) + sg (3200*512) = 16.4 MB f32
    float* wsf = (float*)d_ws;
    float* xn  = wsf;
    float* xcb = xn  + NTOK*DM;
    float* sgb = xcb + NTOK*DI;
    float* out = (float*)d_out;

    const float* cur = x;
    for (int l=0; l<2; ++l){
        ln_kernel<<<NTOK/4, 256, 0, stream>>>(cur, ln_w + l*DM, ln_b + l*DM, xn);
        gemm1_kernel<<<dim3(NX/64, NTOK/64), 256, 0, stream>>>(
            xn, in_w + l*DM*NX, in_b + l*NX,
            cw + l*4*DI + 3*DI, cb + l*DI, xcb, sgb);
        mid_kernel<<<NTOK/16, 256, 0, stream>>>(
            xcb, sgb, xw + l*DI*NPJ, dtw + l*DTR*DI, dtb + l*DI, Dp + l*DI);
        gemm3_kernel<<<dim3(DM/64, NTOK/64), 256, 0, stream>>>(
            xcb, ow + l*DI*DM, ob + l*DM, cur, out);
        cur = out;
    }
}

// Round 2
// 241.521 us; speedup vs baseline: 1.2023x; 1.2023x over previous
//
#include <hip/hip_runtime.h>
#include <math.h>

// Mamba-like block with L=1: scan degenerates (h=dBx), A_log unused,
// depthwise conv reduces to last-tap: xc = silu(xs*conv_w[3] + conv_b).
// Per layer: LN -> GEMM1(256->1024) -> silu/conv -> GEMM2(512->144, split-K)
//   -> bc=Bm.Cm, dt=softplus(dtr@dtw+db) -> y=xc*(dt*bc+D)*silu(gate)
//   -> GEMM3(512->256) + out_b + residual.

#define NTOK 3200   // B*V = 8*400
#define DM   256
#define DI   512
#define NX   1024   // 2*DI
#define DTR  16
#define DS   64
#define NPJ  144    // DTR + 2*DS

__device__ __forceinline__ float sigf(float x){ return 1.0f/(1.0f+expf(-x)); }
__device__ __forceinline__ float siluf(float x){ return x*sigf(x); }
__device__ __forceinline__ float softplusf(float x){ return (x>20.f) ? x : log1pf(expf(x)); }

// ---------------- LayerNorm: one wave per token ----------------
__global__ __launch_bounds__(256) void ln_kernel(
    const float* __restrict__ x, const float* __restrict__ lw,
    const float* __restrict__ lb, float* __restrict__ xn)
{
    const int wave = threadIdx.x >> 6, lane = threadIdx.x & 63;
    const int tok  = blockIdx.x*4 + wave;
    const float4 v = *(const float4*)(x + tok*DM + lane*4);
    float s = v.x+v.y+v.z+v.w;
    #pragma unroll
    for (int o=32;o>=1;o>>=1) s += __shfl_xor(s,o,64);
    const float mu = s*(1.0f/DM);
    const float4 d = {v.x-mu, v.y-mu, v.z-mu, v.w-mu};
    float q = d.x*d.x+d.y*d.y+d.z*d.z+d.w*d.w;
    #pragma unroll
    for (int o=32;o>=1;o>>=1) q += __shfl_xor(q,o,64);
    const float r = rsqrtf(q*(1.0f/DM)+1e-5f);
    const float4 w = *(const float4*)(lw + lane*4);
    const float4 b = *(const float4*)(lb + lane*4);
    const float4 o4 = {d.x*r*w.x+b.x, d.y*r*w.y+b.y, d.z*r*w.z+b.z, d.w*r*w.w+b.w};
    *(float4*)(xn + tok*DM + lane*4) = o4;
}

// ---------------- GEMM1: xn(3200x256) @ in_w(256x1024) + epilogue ----------------
__global__ __launch_bounds__(256) void gemm1_kernel(
    const float* __restrict__ A, const float* __restrict__ W,
    const float* __restrict__ inb, const float* __restrict__ cw3,
    const float* __restrict__ cb, float* __restrict__ xc, float* __restrict__ sg)
{
    __shared__ float As[16][68];
    __shared__ float Bs[16][64];
    const int tid = threadIdx.x;
    const int m0 = blockIdx.y*64, n0 = blockIdx.x*64;
    const int tm = tid>>4, tn = tid&15;
    const int la_m = tid>>2, la_k = (tid&3)*4;
    const int lb_k = tid>>4, lb_n = (tid&15)*4;
    float acc[4][4] = {};
    for (int k0=0;k0<DM;k0+=16){
        const float4 a4 = *(const float4*)(A + (m0+la_m)*DM + k0+la_k);
        As[la_k+0][la_m]=a4.x; As[la_k+1][la_m]=a4.y;
        As[la_k+2][la_m]=a4.z; As[la_k+3][la_m]=a4.w;
        *(float4*)(&Bs[lb_k][lb_n]) = *(const float4*)(W + (k0+lb_k)*NX + n0+lb_n);
        __syncthreads();
        #pragma unroll
        for (int kk=0;kk<16;kk++){
            const float4 a = *(const float4*)(&As[kk][tm*4]);
            const float4 b = *(const float4*)(&Bs[kk][tn*4]);
            const float av[4]={a.x,a.y,a.z,a.w};
            const float bv[4]={b.x,b.y,b.z,b.w};
            #pragma unroll
            for (int i=0;i<4;i++)
                #pragma unroll
                for (int j=0;j<4;j++) acc[i][j]=fmaf(av[i],bv[j],acc[i][j]);
        }
        __syncthreads();
    }
    const int nb = n0 + tn*4;
    #pragma unroll
    for (int i=0;i<4;i++){
        const int m = m0+tm*4+i;
        float4 o;
        float* po = &o.x;
        if (nb < DI){
            #pragma unroll
            for (int j=0;j<4;j++){
                float v = acc[i][j] + inb[nb+j];
                po[j] = siluf(v*cw3[nb+j]+cb[nb+j]);
            }
            *(float4*)(xc + m*DI + nb) = o;
        } else {
            #pragma unroll
            for (int j=0;j<4;j++){
                float v = acc[i][j] + inb[nb+j];
                po[j] = siluf(v);
            }
            *(float4*)(sg + m*DI + (nb-DI)) = o;
        }
    }
}

// ---------------- mid_gemm2: partial = xc(64tok x Kchunk) @ xw(Kchunk x 144) ----------------
// grid (NTOK/64, KS). Tile 64x144, BK=16, 256 threads, acc[4][9].
// Thread (tm,tn) owns rows m0+tm*4..+3, cols {tn*4+0..3, 64+tn*4+0..3, 128+tn}.
// part layout: part[tok][ks*144 + col], token stride S = KS*144.
__global__ __launch_bounds__(256) void mid_gemm2_kernel(
    const float* __restrict__ xc, const float* __restrict__ xw,
    float* __restrict__ part, int KS)
{
    __shared__ union {
        struct { float As[16][68]; float Bs[16*144]; } g;
        float st[32*144];
    } sm;
    const int tid = threadIdx.x;
    const int m0 = blockIdx.x*64;
    const int ks = blockIdx.y;
    const int kw = DI / KS;            // K-chunk width
    const int kbeg = ks*kw;
    const int tm = tid>>4, tn = tid&15;
    const int la_m = tid>>2, la_k = (tid&3)*4;
    float acc[4][9] = {};
    for (int k0=kbeg; k0<kbeg+kw; k0+=16){
        const float4 a4 = *(const float4*)(xc + (m0+la_m)*DI + k0+la_k);
        sm.g.As[la_k+0][la_m]=a4.x; sm.g.As[la_k+1][la_m]=a4.y;
        sm.g.As[la_k+2][la_m]=a4.z; sm.g.As[la_k+3][la_m]=a4.w;
        // 16x144 chunk of xw is contiguous (row-major): 2304 floats = 576 float4
        if (tid < 192){
            #pragma unroll
            for (int i=0;i<3;i++){
                const int f4 = tid + i*192;
                *(float4*)(&sm.g.Bs[f4*4]) = *(const float4*)(xw + k0*NPJ + f4*4);
            }
        }
        __syncthreads();
        #pragma unroll
        for (int kk=0;kk<16;kk++){
            const float4 a = *(const float4*)(&sm.g.As[kk][tm*4]);
            const float4 b0 = *(const float4*)(&sm.g.Bs[kk*NPJ + tn*4]);
            const float4 b1 = *(const float4*)(&sm.g.Bs[kk*NPJ + 64 + tn*4]);
            const float  b2 = sm.g.Bs[kk*NPJ + 128 + tn];
            const float av[4]={a.x,a.y,a.z,a.w};
            const float bv[9]={b0.x,b0.y,b0.z,b0.w,b1.x,b1.y,b1.z,b1.w,b2};
            #pragma unroll
            for (int i=0;i<4;i++)
                #pragma unroll
                for (int j=0;j<9;j++) acc[i][j]=fmaf(av[i],bv[j],acc[i][j]);
        }
        __syncthreads();
    }
    // epilogue: stage 32 rows at a time into LDS, copy out coalesced
    const int S = KS*NPJ;
    #pragma unroll
    for (int p=0;p<2;p++){
        if (tm>=p*8 && tm<p*8+8){
            #pragma unroll
            for (int i=0;i<4;i++){
                const int lr = tm*4+i - p*32;
                #pragma unroll
                for (int j=0;j<9;j++){
                    const int col = (j<4) ? tn*4+j : ((j<8) ? 64+tn*4+(j-4) : 128+tn);
                    sm.st[lr*NPJ + col] = acc[i][j];
                }
            }
        }
        __syncthreads();
        // 32*144 = 4608 floats = 1152 float4
        #pragma unroll
        for (int i=0;i<5;i++){
            const int f4 = tid + i*256;
            if (f4 < 1152){
                const int lr = f4/36, c4 = f4%36;
                *(float4*)(part + (size_t)(m0 + p*32 + lr)*S + ks*NPJ + c4*4) =
                    *(const float4*)(&sm.st[lr*NPJ + c4*4]);
            }
        }
        __syncthreads();
    }
}

// ---------------- mid_fin: reduce partials + bc + dt + y ----------------
// grid NTOK/16, 256 threads: 16 tokens/block, 16 threads/token.
__global__ __launch_bounds__(256) void mid_fin_kernel(
    float* __restrict__ xc, const float* __restrict__ sg,
    const float* __restrict__ part, const float* __restrict__ dtw,
    const float* __restrict__ dtb, const float* __restrict__ Dp, int KS)
{
    __shared__ float dbl[16][145];
    __shared__ float bcs[16];
    const int tid = threadIdx.x;
    const int tt = tid>>4, tc = tid&15;
    const int tok = blockIdx.x*16 + tt;
    const int S = KS*NPJ;
    #pragma unroll
    for (int j=0;j<9;j++){
        const int col = tc + j*16;
        float s = 0.f;
        for (int ks=0; ks<KS; ++ks) s += part[(size_t)tok*S + ks*NPJ + col];
        dbl[tt][col] = s;
    }
    __syncthreads();
    // bc = dot(Bm, Cm)
    float p = 0.f;
    #pragma unroll
    for (int jj=0;jj<4;jj++){
        const int s = tc*4+jj;
        p += dbl[tt][DTR+s]*dbl[tt][DTR+DS+s];
    }
    #pragma unroll
    for (int m=8;m>=1;m>>=1) p += __shfl_xor(p,m,64);
    if (tc==0) bcs[tt]=p;
    __syncthreads();
    const float bc = bcs[tt];
    float dtr[DTR];
    #pragma unroll
    for (int r=0;r<DTR;r++) dtr[r]=dbl[tt][r];
    // each thread: channels d = tc*32 .. tc*32+31, float4 granularity
    #pragma unroll
    for (int j4=0;j4<8;j4++){
        const int d0 = tc*32 + j4*4;
        float4 dv = *(const float4*)(dtb + d0);
        #pragma unroll
        for (int r=0;r<DTR;r++){
            const float4 w = *(const float4*)(dtw + r*DI + d0);
            dv.x = fmaf(dtr[r], w.x, dv.x);
            dv.y = fmaf(dtr[r], w.y, dv.y);
            dv.z = fmaf(dtr[r], w.z, dv.z);
            dv.w = fmaf(dtr[r], w.w, dv.w);
        }
        dv.x = softplusf(dv.x); dv.y = softplusf(dv.y);
        dv.z = softplusf(dv.z); dv.w = softplusf(dv.w);
        const float4 xcv = *(const float4*)(xc + (size_t)tok*DI + d0);
        const float4 sgv = *(const float4*)(sg + (size_t)tok*DI + d0);
        const float4 Dv  = *(const float4*)(Dp + d0);
        float4 y;
        y.x = xcv.x*(dv.x*bc + Dv.x)*sgv.x;
        y.y = xcv.y*(dv.y*bc + Dv.y)*sgv.y;
        y.z = xcv.z*(dv.z*bc + Dv.z)*sgv.z;
        y.w = xcv.w*(dv.w*bc + Dv.w)*sgv.w;
        *(float4*)(xc + (size_t)tok*DI + d0) = y;
    }
}

// ---------------- GEMM3: y(3200x512) @ out_w(512x256) + out_b + residual ----------------
__global__ __launch_bounds__(256) void gemm3_kernel(
    const float* __restrict__ A, const float* __restrict__ W,
    const float* __restrict__ ob, const float* __restrict__ res,
    float* __restrict__ out)
{
    __shared__ float As[16][68];
    __shared__ float Bs[16][64];
    const int tid = threadIdx.x;
    const int m0 = blockIdx.y*64, n0 = blockIdx.x*64;
    const int tm = tid>>4, tn = tid&15;
    const int la_m = tid>>2, la_k = (tid&3)*4;
    const int lb_k = tid>>4, lb_n = (tid&15)*4;
    float acc[4][4] = {};
    for (int k0=0;k0<DI;k0+=16){
        const float4 a4 = *(const float4*)(A + (m0+la_m)*DI + k0+la_k);
        As[la_k+0][la_m]=a4.x; As[la_k+1][la_m]=a4.y;
        As[la_k+2][la_m]=a4.z; As[la_k+3][la_m]=a4.w;
        *(float4*)(&Bs[lb_k][lb_n]) = *(const float4*)(W + (k0+lb_k)*DM + n0+lb_n);
        __syncthreads();
        #pragma unroll
        for (int kk=0;kk<16;kk++){
            const float4 a = *(const float4*)(&As[kk][tm*4]);
            const float4 b = *(const float4*)(&Bs[kk][tn*4]);
            const float av[4]={a.x,a.y,a.z,a.w};
            const float bv[4]={b.x,b.y,b.z,b.w};
            #pragma unroll
            for (int i=0;i<4;i++)
                #pragma unroll
                for (int j=0;j<4;j++) acc[i][j]=fmaf(av[i],bv[j],acc[i][j]);
        }
        __syncthreads();
    }
    const int nb = n0 + tn*4;
    #pragma unroll
    for (int i=0;i<4;i++){
        const int m = m0+tm*4+i;
        const float4 rv = *(const float4*)(res + m*DM + nb);
        float4 o;
        o.x = acc[i][0] + ob[nb+0] + rv.x;
        o.y = acc[i][1] + ob[nb+1] + rv.y;
        o.z = acc[i][2] + ob[nb+2] + rv.z;
        o.w = acc[i][3] + ob[nb+3] + rv.w;
        *(float4*)(out + m*DM + nb) = o;
    }
}

extern "C" void kernel_launch(void* const* d_in, const int* in_sizes, int n_in,
                              void* d_out, int out_size, void* d_ws, size_t ws_size,
                              hipStream_t stream)
{
    const float* x    = (const float*)d_in[0];
    const float* ln_w = (const float*)d_in[1];
    const float* ln_b = (const float*)d_in[2];
    const float* in_w = (const float*)d_in[3];
    const float* in_b = (const float*)d_in[4];
    const float* cw   = (const float*)d_in[5];
    const float* cb   = (const float*)d_in[6];
    const float* xw   = (const float*)d_in[7];
    const float* dtw  = (const float*)d_in[8];
    const float* dtb  = (const float*)d_in[9];
    // d_in[10] = A_log: UNUSED. L==1 => scan state starts at 0, dA multiplies h0=0.
    const float* Dp   = (const float*)d_in[11];
    const float* ow   = (const float*)d_in[12];
    const float* ob   = (const float*)d_in[13];

    float* wsf = (float*)d_ws;
    float* xn  = wsf;                      // 3200*256
    float* xcb = xn  + NTOK*DM;            // 3200*512
    float* sgb = xcb + NTOK*DI;            // 3200*512
    float* prt = sgb + NTOK*DI;            // 3200*144*KS
    float* out = (float*)d_out;

    // pick split-K count that fits the workspace (deterministic: ws_size fixed)
    const size_t baseF = (size_t)NTOK*DM + 2ull*NTOK*DI;
    int KS = 4;
    while (KS > 1 && (baseF + (size_t)NTOK*NPJ*KS)*4 > ws_size) KS >>= 1;

    const float* cur = x;
    for (int l=0; l<2; ++l){
        ln_kernel<<<NTOK/4, 256, 0, stream>>>(cur, ln_w + l*DM, ln_b + l*DM, xn);
        gemm1_kernel<<<dim3(NX/64, NTOK/64), 256, 0, stream>>>(
            xn, in_w + l*DM*NX, in_b + l*NX,
            cw + l*4*DI + 3*DI, cb + l*DI, xcb, sgb);
        mid_gemm2_kernel<<<dim3(NTOK/64, KS), 256, 0, stream>>>(
            xcb, xw + l*DI*NPJ, prt, KS);
        mid_fin_kernel<<<NTOK/16, 256, 0, stream>>>(
            xcb, sgb, prt, dtw + l*DTR*DI, dtb + l*DI, Dp + l*DI, KS);
        gemm3_kernel<<<dim3(DM/64, NTOK/64), 256, 0, stream>>>(
            xcb, ow + l*DI*DM, ob + l*DM, cur, out);
        cur = out;
    }
}